// Round 4
// baseline (261.153 us; speedup 1.0000x reference)
//
#include <hip/hip_runtime.h>

// SortPredictionByEta: B=64, V=16384, F=32, C=4
// out[b,v,j] = frac[b,v, perm[b,j]] where perm ranks f by weighted eta ascending.

constexpr int B = 64;
constexpr int V = 16384;
constexpr int F = 32;
constexpr int NCHUNK = 16;          // V-chunks per batch for deterministic reduction
constexpr int CHUNK = V / NCHUNK;   // 1024 rows per block

typedef float vfloat4 __attribute__((ext_vector_type(4)));  // builtin-compatible

// ---------------- Kernel 1: partial reductions over V ----------------
// Unchanged from R2 (bit-exact ranking). grid=(NCHUNK,B), block=256.
__global__ __launch_bounds__(256) void k_reduce(
    const float* __restrict__ frac, const float* __restrict__ feat,
    float* __restrict__ p1, float* __restrict__ p2)
{
    const int b     = blockIdx.y;
    const int chunk = blockIdx.x;
    const int tid   = threadIdx.x;
    const int v0    = chunk * CHUNK;

    __shared__ float2 sfeat[CHUNK];                // 8 KiB: {e, e*eta} per row
    const float4* feat4 = reinterpret_cast<const float4*>(feat);
    #pragma unroll
    for (int i = 0; i < CHUNK / 256; ++i) {
        const int r = tid + i * 256;
        const float4 f = feat4[b * V + v0 + r];    // coalesced 16B/lane
        sfeat[r] = make_float2(f.x, f.x * f.y);
    }
    __syncthreads();

    const int g = tid & 7;
    const int w = tid >> 3;
    float4 a1 = make_float4(0.f, 0.f, 0.f, 0.f);
    float4 a2 = make_float4(0.f, 0.f, 0.f, 0.f);
    const float4* frac4 = reinterpret_cast<const float4*>(frac);

    for (int r = w; r < CHUNK; r += 32) {
        const float2 ee = sfeat[r];                // broadcast across 8 g-lanes
        const float4 fr = frac4[(b * V + v0 + r) * 8 + g];
        a1.x += ee.x * fr.x; a1.y += ee.x * fr.y; a1.z += ee.x * fr.z; a1.w += ee.x * fr.w;
        a2.x += ee.y * fr.x; a2.y += ee.y * fr.y; a2.z += ee.y * fr.z; a2.w += ee.y * fr.w;
    }

    __shared__ float red[2][32][33];               // +1 pad: conflict-free reads
    const int f0 = 4 * g;
    red[0][w][f0+0] = a1.x; red[0][w][f0+1] = a1.y; red[0][w][f0+2] = a1.z; red[0][w][f0+3] = a1.w;
    red[1][w][f0+0] = a2.x; red[1][w][f0+1] = a2.y; red[1][w][f0+2] = a2.z; red[1][w][f0+3] = a2.w;
    __syncthreads();

    if (tid < 64) {
        const int which = tid >> 5;
        const int f     = tid & 31;
        float s = 0.f;
        #pragma unroll
        for (int j = 0; j < 32; ++j) s += red[which][j][f];
        float* dst = which ? p2 : p1;
        dst[(b * NCHUNK + chunk) * F + f] = s;
    }
}

// ---------------- Kernel 2: finalize + rank-sort (tiny) ----------------
// grid = (B), block = 64. Computes perm once so permute blocks don't
// redundantly re-read 4 KiB of partials each (R2 wasted ~64 MiB of L2 reads).
__global__ __launch_bounds__(64) void k_sort(
    const float* __restrict__ p1, const float* __restrict__ p2,
    int* __restrict__ perm)
{
    const int b   = blockIdx.x;
    const int tid = threadIdx.x;
    __shared__ float wv[32];

    if (tid < 32) {
        float s1 = 0.f, s2 = 0.f;
        #pragma unroll
        for (int c = 0; c < NCHUNK; ++c) {
            s1 += p1[(b * NCHUNK + c) * F + tid];
            s2 += p2[(b * NCHUNK + c) * F + tid];
        }
        float we = s2 / (s1 + 1e-7f);
        // jnp.where(|we|>0.1, we, 500); NaN compares false -> 500 (matches jnp)
        we = (fabsf(we) > 0.1f) ? we : 500.0f;
        wv[tid] = we;
    }
    __syncthreads();

    if (tid < 32) {
        const float my = wv[tid];
        int rank = 0;
        #pragma unroll
        for (int j = 0; j < 32; ++j) {
            const float vj = wv[j];
            // ascending; ties broken by lower index first (top_k stability)
            rank += (vj < my || (vj == my && j < tid)) ? 1 : 0;
        }
        perm[b * F + rank] = tid;
    }
}

// ---------------- Kernel 3: apply permutation ----------------
// grid = (V/256, B) = 4096 blocks, block = 256. Each block: 4 sub-tiles of
// 64 rows, double-buffered LDS staging, nontemporal float4 stores (out is
// write-once; keep frac resident in L3 for the re-read).
__global__ __launch_bounds__(256) void k_permute(
    const float* __restrict__ frac, const int* __restrict__ perm,
    float* __restrict__ out)
{
    const int b   = blockIdx.y;
    const int tid = threadIdx.x;

    __shared__ int   pm[32];
    __shared__ float tile[2][64 * 36];             // stride 36: aligned, spread banks

    if (tid < 32) pm[tid] = perm[b * F + tid];
    __syncthreads();

    const int rr = tid >> 3, qq = tid & 7;
    const int j0 = pm[4*qq+0], j1 = pm[4*qq+1], j2 = pm[4*qq+2], j3 = pm[4*qq+3];

    const float4* frac4 = reinterpret_cast<const float4*>(frac);
    vfloat4*      out4  = reinterpret_cast<vfloat4*>(out);

    #pragma unroll
    for (int t = 0; t < 4; ++t) {
        float* tl = tile[t & 1];
        const int vbase = (blockIdx.x * 4 + t) * 64;
        const int rowbase = b * V + vbase;
        // stage 64 rows, coalesced 16B/lane
        #pragma unroll
        for (int i = 0; i < 2; ++i) {
            const int r2 = rr + i * 32;
            *reinterpret_cast<float4*>(&tl[r2 * 36 + qq * 4]) =
                frac4[(rowbase + r2) * 8 + qq];
        }
        __syncthreads();
        #pragma unroll
        for (int i = 0; i < 2; ++i) {
            const int r2 = rr + i * 32;
            vfloat4 o;
            o.x = tl[r2 * 36 + j0];
            o.y = tl[r2 * 36 + j1];
            o.z = tl[r2 * 36 + j2];
            o.w = tl[r2 * 36 + j3];
            __builtin_nontemporal_store(o, &out4[(rowbase + r2) * 8 + qq]);
        }
        __syncthreads();   // guards this buffer's readers vs t+2's writers
    }
}

extern "C" void kernel_launch(void* const* d_in, const int* in_sizes, int n_in,
                              void* d_out, int out_size, void* d_ws, size_t ws_size,
                              hipStream_t stream)
{
    const float* frac = (const float*)d_in[0];   // (B,V,F) f32
    const float* feat = (const float*)d_in[1];   // (B,V,C) f32
    float* out = (float*)d_out;                  // (B,V,F) f32

    // workspace: p1[B][NCHUNK][F], p2[B][NCHUNK][F], perm[B][F]
    float* p1   = (float*)d_ws;
    float* p2   = p1 + B * NCHUNK * F;
    int*   perm = (int*)(p2 + B * NCHUNK * F);

    k_reduce <<<dim3(NCHUNK, B), 256, 0, stream>>>(frac, feat, p1, p2);
    k_sort   <<<dim3(B),          64, 0, stream>>>(p1, p2, perm);
    k_permute<<<dim3(V / 256, B), 256, 0, stream>>>(frac, perm, out);
}